// Round 3
// baseline (287.742 us; speedup 1.0000x reference)
//
#include <hip/hip_runtime.h>
#include <cstdint>
#include <cstddef>

// ---------------------------------------------------------------------------
// logsumexp_m[ -0.5*||(s_n - x_m)/std||^2 ] + logc - log M   (N=8192,M=4096,D=784)
// R6b: identical to R6 (container infra flake on R6 run — resubmit for data).
// 256x256 tile, 8 waves (wave = 128x64), 32x32x64 MX-fp8 MFMA,
// kt64 ring of 3 x 32KB LDS slots, 2-barrier/K-step schedule with counted
// vmcnt (8->4->0), 14 K-steps. R2 conflict-free slot swizzle kept.
// Epilogue: j-combine + shfl_xor(16) -> [256][64] float2 overlay (128KB),
// rotated scan, 16 partials/row.
// ---------------------------------------------------------------------------

#define N_ROWS 8192
#define M_ROWS 4096
#define D_DIM  784
#define KPB    896        // K bytes per row (fp8), padded 784 -> 14*64
#define LOG2PI 1.8378770664093453f
#define LOGM   8.317766166719343f   // log(4096)

typedef unsigned char u8;
typedef __attribute__((ext_vector_type(8)))  int   i32x8;
typedef __attribute__((ext_vector_type(16))) float f32x16;

__device__ __forceinline__ void gld16(const u8* g, u8* l) {
    __builtin_amdgcn_global_load_lds(
        (__attribute__((address_space(1))) void*)(void*)g,
        (__attribute__((address_space(3))) void*)l, 16, 0, 0);
}

// ------------- k_prep: scale, fp8-round, row norms (wave x 2 rows) ---------
__global__ __launch_bounds__(256) void k_prep(const float* __restrict__ samples,
                                              const float* __restrict__ x,
                                              const float* __restrict__ stdv,
                                              u8* __restrict__ dst,
                                              float* __restrict__ norm) {
    const int wid = threadIdx.x >> 6, lane = threadIdx.x & 63;
    const int row0 = blockIdx.x * 8 + wid * 2;

    float4 rstd[4];
#pragma unroll
    for (int i = 0; i < 4; ++i) {
        int c = lane + 64 * i;
        rstd[i] = make_float4(1.f, 1.f, 1.f, 1.f);
        if (c < 196) {
            float4 d = ((const float4*)stdv)[c];
            rstd[i] = make_float4(1.f / d.x, 1.f / d.y, 1.f / d.z, 1.f / d.w);
        }
    }

#pragma unroll
    for (int rr = 0; rr < 2; ++rr) {
        const int row = row0 + rr;
        const float* src = (row < N_ROWS) ? samples + (size_t)row * D_DIM
                                          : x + (size_t)(row - N_ROWS) * D_DIM;
        unsigned* drow = (unsigned*)(dst + (size_t)row * KPB);
        float sq = 0.f;
#pragma unroll
        for (int i = 0; i < 4; ++i) {
            const int c = lane + 64 * i;       // u32 chunk (4 fp8)
            if (c < 224) {                     // 224*4 = 896 = KPB
                unsigned p = 0;
                if (c < 196) {                 // 196*4 = 784 = D
                    float4 s = ((const float4*)src)[c];
                    float ux = s.x * rstd[i].x, uy = s.y * rstd[i].y;
                    float uz = s.z * rstd[i].z, uw = s.w * rstd[i].w;
                    p = __builtin_amdgcn_cvt_pk_fp8_f32(ux, uy, 0, false);
                    p = __builtin_amdgcn_cvt_pk_fp8_f32(uz, uw, p, true);
                    float r0 = __builtin_amdgcn_cvt_f32_fp8(p, 0);
                    float r1 = __builtin_amdgcn_cvt_f32_fp8(p, 1);
                    float r2 = __builtin_amdgcn_cvt_f32_fp8(p, 2);
                    float r3 = __builtin_amdgcn_cvt_f32_fp8(p, 3);
                    sq += r0 * r0 + r1 * r1 + r2 * r2 + r3 * r3;  // norm of ROUNDED
                }
                drow[c] = p;
            }
        }
        for (int m = 32; m; m >>= 1) sq += __shfl_xor(sq, m);
        if (lane == 0) norm[row] = sq;
    }
}

// ---------------- k_gemm: 256x256 tile, 32x32x64 MX-fp8, kt64 ring ---------
// LDS slots s=0..2 at s*32768: A 256x64B at +0, B 256x64B at +16384.
// Slot chunk c of row r holds global K-granule c ^ ((r>>1)&3)  (R2 swizzle).
// A-frag (32x32x64): lane l: row = l&31, K-bytes [32*(l>>5), +32) = LDS
// chunks {(2h)^key, +^1} -> b128 at addr and addr^16.  B identical on cols.
// C/D: col = lane&31, row = (reg&3) + 8*(reg>>2) + 4*(lane>>5).
__global__ __launch_bounds__(512, 2) void k_gemm(const u8* __restrict__ U,
                                                 const u8* __restrict__ V,
                                                 const float* __restrict__ vnorm,
                                                 float* __restrict__ pmax,
                                                 float* __restrict__ psum) {
    __shared__ __align__(16) char smem[131072];  // 96K ring + epilogue overlay
    float2* part = (float2*)smem;                // [256][64] epilogue partials

    const int tid = threadIdx.x;
    const int lane = tid & 63;
    const int wid = tid >> 6;              // 0..7
    const int waveRow = wid >> 2;          // 0..1 (128-row half)
    const int waveCol = wid & 3;           // 0..3 (64-col quarter)
    const int bCol = blockIdx.x;           // 0..15
    const int bRow = blockIdx.y;           // 0..31
    const int lr = lane & 31, h = lane >> 5;

    // ---- staging: per kt64, 2 A + 2 B gld16/thread. Inst q: wave covers
    // rows wid*32+q*16+(lane>>2), chunk lane&3; source granule pre-swizzled.
    const int r4 = lane >> 2;
    const int gc = (lane & 3) ^ ((lane >> 3) & 3);
    const u8* gA[2]; const u8* gB[2]; int lo[2];
#pragma unroll
    for (int q = 0; q < 2; ++q) {
        const int row = wid * 32 + q * 16 + r4;     // 0..255
        gA[q] = U + (size_t)(bRow * 256 + row) * KPB + gc * 16;
        gB[q] = V + (size_t)(bCol * 256 + row) * KPB + gc * 16;
        lo[q] = wid * 2048 + q * 1024;              // wave-uniform LDS offset
    }

    // ---- frag-read offsets
    const int key = (lr >> 1) & 3;
    const int slotL = (2 * h) ^ key;
    const int aoff = (waveRow * 128 + lr) * 64 + slotL * 16;           // +i*2048
    const int boff = 16384 + (waveCol * 64 + lr) * 64 + slotL * 16;    // +j*2048

    f32x16 acc[4][2];
#pragma unroll
    for (int i = 0; i < 4; ++i)
#pragma unroll
        for (int j = 0; j < 2; ++j)
#pragma unroll
            for (int r = 0; r < 16; ++r) acc[i][j][r] = 0.f;

#define ISSUE(u) { \
    u8* lb = (u8*)smem + ((u) % 3) * 32768; \
    const int ko = (u) * 64; \
    gld16(gA[0] + ko, lb + lo[0]); \
    gld16(gB[0] + ko, lb + 16384 + lo[0]); \
    gld16(gA[1] + ko, lb + lo[1]); \
    gld16(gB[1] + ko, lb + 16384 + lo[1]); }

    ISSUE(0); ISSUE(1);                    // 8 loads in flight

#pragma unroll
    for (int kt = 0; kt < 14; ++kt) {
        if (kt < 12) {
            ISSUE(kt + 2);                              // depth-2 prefetch
            __builtin_amdgcn_s_waitcnt(0x0F78);         // vmcnt(8): kt landed
        } else if (kt == 12) {
            __builtin_amdgcn_s_waitcnt(0x0F74);         // vmcnt(4)
        } else {
            __builtin_amdgcn_s_waitcnt(0x0F70);         // vmcnt(0)
        }
        __builtin_amdgcn_s_barrier();                   // all waves staged kt

        const char* base = smem + (kt % 3) * 32768;
        i32x8 a[4], b[2];
#pragma unroll
        for (int i = 0; i < 4; ++i) {
            int4 L = *(const int4*)(base + (aoff + i * 2048));
            int4 H = *(const int4*)(base + ((aoff + i * 2048) ^ 16));
            a[i] = (i32x8){L.x, L.y, L.z, L.w, H.x, H.y, H.z, H.w};
        }
#pragma unroll
        for (int j = 0; j < 2; ++j) {
            int4 L = *(const int4*)(base + (boff + j * 2048));
            int4 H = *(const int4*)(base + ((boff + j * 2048) ^ 16));
            b[j] = (i32x8){L.x, L.y, L.z, L.w, H.x, H.y, H.z, H.w};
        }
#pragma unroll
        for (int i = 0; i < 4; ++i)
#pragma unroll
            for (int j = 0; j < 2; ++j)
                acc[i][j] = __builtin_amdgcn_mfma_scale_f32_32x32x64_f8f6f4(
                    a[i], b[j], acc[i][j], 0 /*fp8*/, 0 /*fp8*/,
                    0, 127 /*scaleA=1*/, 0, 127 /*scaleB=1*/);

        __builtin_amdgcn_s_barrier();                   // readers of slot done
    }
#undef ISSUE

    // ---- epilogue ----
    const float vn0 = vnorm[bCol * 256 + waveCol * 64 + lr];
    const float vn1 = vnorm[bCol * 256 + waveCol * 64 + 32 + lr];
    __syncthreads();   // drain before partials overlay the ring

    // j-combine (2 cols) then pair-combine with lane^16 (4 cols) -> write.
#pragma unroll
    for (int i = 0; i < 4; ++i) {
#pragma unroll
        for (int r = 0; r < 16; ++r) {
            float w0 = acc[i][0][r] - 0.5f * vn0;
            float w1 = acc[i][1][r] - 0.5f * vn1;
            float m = fmaxf(w0, w1);
            float s = __expf(w0 - m) + __expf(w1 - m);
            float mo = __shfl_xor(m, 16);
            float so = __shfl_xor(s, 16);
            float M = fmaxf(m, mo);
            s = s * __expf(m - M) + so * __expf(mo - M);
            if (lr < 16) {
                const int rin = (r & 3) + 8 * (r >> 2) + 4 * h;
                part[(waveRow * 128 + i * 32 + rin) * 64 + (waveCol * 16 + lr)] =
                    make_float2(M, s);
            }
        }
    }
    __syncthreads();
    {
        const int row = tid >> 1, half = tid & 1;
        const float2* p = part + row * 64 + half * 32;
        float m = -3.4e38f;
#pragma unroll 8
        for (int q = 0; q < 32; ++q) m = fmaxf(m, p[(q + row) & 31].x);
        float s = 0.f;
#pragma unroll 8
        for (int q = 0; q < 32; ++q) { float2 v = p[(q + row) & 31]; s += v.y * __expf(v.x - m); }
        float mo = __shfl_xor(m, 1);
        float so = __shfl_xor(s, 1);
        float M = fmaxf(m, mo);
        s = s * __expf(m - M) + so * __expf(mo - M);
        if (half == 0) {
            size_t grow = (size_t)(bRow * 256 + row);
            pmax[grow * 16 + bCol] = M;
            psum[grow * 16 + bCol] = s;
        }
    }
}

// --------------- k_final: combine 16 partials + row constants --------------
__global__ __launch_bounds__(256) void k_final(const float* __restrict__ pmax,
                                               const float* __restrict__ psum,
                                               const float* __restrict__ norm,
                                               const float* __restrict__ stdv,
                                               float* __restrict__ out) {
    __shared__ float wsum[4];
    const int t = threadIdx.x;
    float ls = 0.f;
    for (int d = t; d < D_DIM; d += 256) ls += logf(stdv[d]);
    for (int m = 32; m; m >>= 1) ls += __shfl_xor(ls, m);
    if ((t & 63) == 0) wsum[t >> 6] = ls;
    __syncthreads();
    const float logc = -0.5f * (float)D_DIM * LOG2PI - (wsum[0] + wsum[1] + wsum[2] + wsum[3]);

    const int n = blockIdx.x * 256 + t;
    const float* pm = pmax + (size_t)n * 16;
    const float* ps = psum + (size_t)n * 16;
    float gm = pm[0];
#pragma unroll
    for (int c = 1; c < 16; ++c) gm = fmaxf(gm, pm[c]);
    float S = 0.f;
#pragma unroll
    for (int c = 0; c < 16; ++c) S += ps[c] * __expf(pm[c] - gm);
    out[n] = gm + logf(S) - 0.5f * norm[n] + logc - LOGM;
}

// ---------------------------------------------------------------------------
extern "C" void kernel_launch(void* const* d_in, const int* in_sizes, int n_in,
                              void* d_out, int out_size, void* d_ws, size_t ws_size,
                              hipStream_t stream) {
    const float* samples = (const float*)d_in[0];  // 8192*784
    const float* x       = (const float*)d_in[1];  // 4096*784
    const float* stdv    = (const float*)d_in[2];  // 784
    float* out = (float*)d_out;                    // 8192

    char* ws = (char*)d_ws;
    // U fp8 (8192*896) | V fp8 (4096*896) | norm (12288 f32) | pmax | psum
    u8*    U    = (u8*)ws;                        //  7,340,032 B
    u8*    V    = (u8*)(ws + 7340032);            //  3,670,016 B
    float* norm = (float*)(ws + 11010048);        //     49,152 B
    float* pmax = (float*)(ws + 11059200);        //    524,288 B
    float* psum = (float*)(ws + 11583488);        //    524,288 B  (total ~12.1 MB)

    k_prep<<<(N_ROWS + M_ROWS) / 8, 256, 0, stream>>>(samples, x, stdv, U, norm);
    k_gemm<<<dim3(M_ROWS / 256, N_ROWS / 256), 512, 0, stream>>>(U, V, norm + N_ROWS, pmax, psum);
    k_final<<<N_ROWS / 256, 256, 0, stream>>>(pmax, psum, norm, stdv, out);
}

// Round 4
// 260.701 us; speedup vs baseline: 1.1037x; 1.1037x over previous
//
#include <hip/hip_runtime.h>
#include <cstdint>
#include <cstddef>

// ---------------------------------------------------------------------------
// logsumexp_m[ -0.5*||(s_n - x_m)/std||^2 ] + logc - log M   (N=8192,M=4096,D=784)
// R7: R6 structure (256x256 tile, 8 waves, 32x32x64 MX-fp8, kt64 ring of
// 3 x 32KB slots, counted vmcnt 8->4->0, 14 K-steps) with the main-loop
// REGISTER-PHASE SPLIT that removes R6's spill: b0,b1 loaded once per kt,
// then 2 phases of {a-pair ds_read -> 4 MFMA} fenced by sched_barrier(0).
// (R6 held a[4]+b[2]+temps live at the 256-VGPR cap -> ~380MB scratch
// traffic each way; R5's phase pattern at the same acc footprint did not
// spill.)  Epilogue unchanged from R6 (verified): j-combine + shfl_xor(16)
// -> [256][64] float2 overlay, rotated scan, 16 partials/row.
// ---------------------------------------------------------------------------

#define N_ROWS 8192
#define M_ROWS 4096
#define D_DIM  784
#define KPB    896        // K bytes per row (fp8), padded 784 -> 14*64
#define LOG2PI 1.8378770664093453f
#define LOGM   8.317766166719343f   // log(4096)

typedef unsigned char u8;
typedef __attribute__((ext_vector_type(8)))  int   i32x8;
typedef __attribute__((ext_vector_type(16))) float f32x16;

__device__ __forceinline__ void gld16(const u8* g, u8* l) {
    __builtin_amdgcn_global_load_lds(
        (__attribute__((address_space(1))) void*)(void*)g,
        (__attribute__((address_space(3))) void*)l, 16, 0, 0);
}

// ------------- k_prep: scale, fp8-round, row norms (wave x 2 rows) ---------
__global__ __launch_bounds__(256) void k_prep(const float* __restrict__ samples,
                                              const float* __restrict__ x,
                                              const float* __restrict__ stdv,
                                              u8* __restrict__ dst,
                                              float* __restrict__ norm) {
    const int wid = threadIdx.x >> 6, lane = threadIdx.x & 63;
    const int row0 = blockIdx.x * 8 + wid * 2;

    float4 rstd[4];
#pragma unroll
    for (int i = 0; i < 4; ++i) {
        int c = lane + 64 * i;
        rstd[i] = make_float4(1.f, 1.f, 1.f, 1.f);
        if (c < 196) {
            float4 d = ((const float4*)stdv)[c];
            rstd[i] = make_float4(1.f / d.x, 1.f / d.y, 1.f / d.z, 1.f / d.w);
        }
    }

#pragma unroll
    for (int rr = 0; rr < 2; ++rr) {
        const int row = row0 + rr;
        const float* src = (row < N_ROWS) ? samples + (size_t)row * D_DIM
                                          : x + (size_t)(row - N_ROWS) * D_DIM;
        unsigned* drow = (unsigned*)(dst + (size_t)row * KPB);
        float sq = 0.f;
#pragma unroll
        for (int i = 0; i < 4; ++i) {
            const int c = lane + 64 * i;       // u32 chunk (4 fp8)
            if (c < 224) {                     // 224*4 = 896 = KPB
                unsigned p = 0;
                if (c < 196) {                 // 196*4 = 784 = D
                    float4 s = ((const float4*)src)[c];
                    float ux = s.x * rstd[i].x, uy = s.y * rstd[i].y;
                    float uz = s.z * rstd[i].z, uw = s.w * rstd[i].w;
                    p = __builtin_amdgcn_cvt_pk_fp8_f32(ux, uy, 0, false);
                    p = __builtin_amdgcn_cvt_pk_fp8_f32(uz, uw, p, true);
                    float r0 = __builtin_amdgcn_cvt_f32_fp8(p, 0);
                    float r1 = __builtin_amdgcn_cvt_f32_fp8(p, 1);
                    float r2 = __builtin_amdgcn_cvt_f32_fp8(p, 2);
                    float r3 = __builtin_amdgcn_cvt_f32_fp8(p, 3);
                    sq += r0 * r0 + r1 * r1 + r2 * r2 + r3 * r3;  // norm of ROUNDED
                }
                drow[c] = p;
            }
        }
        for (int m = 32; m; m >>= 1) sq += __shfl_xor(sq, m);
        if (lane == 0) norm[row] = sq;
    }
}

// ---------------- k_gemm: 256x256 tile, 32x32x64 MX-fp8, kt64 ring ---------
// LDS slots s=0..2 at s*32768: A 256x64B at +0, B 256x64B at +16384.
// Slot chunk c of row r holds global K-granule c ^ ((r>>1)&3)  (R2 swizzle).
// A-frag (32x32x64): lane l: row = l&31, K-bytes [32*(l>>5), +32) = LDS
// chunks {(2h)^key, ^1} -> b128 at addr and addr^16.  B identical on cols.
// C/D: col = lane&31, row = (reg&3) + 8*(reg>>2) + 4*(lane>>5).
__global__ __launch_bounds__(512, 2) void k_gemm(const u8* __restrict__ U,
                                                 const u8* __restrict__ V,
                                                 const float* __restrict__ vnorm,
                                                 float* __restrict__ pmax,
                                                 float* __restrict__ psum) {
    __shared__ __align__(16) char smem[131072];  // 96K ring + epilogue overlay
    float2* part = (float2*)smem;                // [256][64] epilogue partials

    const int tid = threadIdx.x;
    const int lane = tid & 63;
    const int wid = tid >> 6;              // 0..7
    const int waveRow = wid >> 2;          // 0..1 (128-row half)
    const int waveCol = wid & 3;           // 0..3 (64-col quarter)
    const int bCol = blockIdx.x;           // 0..15
    const int bRow = blockIdx.y;           // 0..31
    const int lr = lane & 31, h = lane >> 5;

    // ---- staging: per kt64, 2 A + 2 B gld16/thread. Inst q: wave covers
    // rows wid*32+q*16+(lane>>2), chunk lane&3; source granule pre-swizzled.
    // B pointers folded into wave-uniform delta dBA (SGPR) to cut VGPRs.
    const int r4 = lane >> 2;
    const int gc = (lane & 3) ^ ((lane >> 3) & 3);
    const u8* gA[2]; int lo[2];
#pragma unroll
    for (int q = 0; q < 2; ++q) {
        const int row = wid * 32 + q * 16 + r4;     // 0..255
        gA[q] = U + (size_t)(bRow * 256 + row) * KPB + gc * 16;
        lo[q] = wid * 2048 + q * 1024;              // wave-uniform LDS offset
    }
    const ptrdiff_t dBA = (V - U) +
        ((ptrdiff_t)bCol * 256 - (ptrdiff_t)bRow * 256) * (ptrdiff_t)KPB;

    // ---- frag-read offsets
    const int key = (lr >> 1) & 3;
    const int slotL = (2 * h) ^ key;
    const int aoff = (waveRow * 128 + lr) * 64 + slotL * 16;           // +i*2048
    const int boff = 16384 + (waveCol * 64 + lr) * 64 + slotL * 16;    // +j*2048

    f32x16 acc[4][2];
#pragma unroll
    for (int i = 0; i < 4; ++i)
#pragma unroll
        for (int j = 0; j < 2; ++j)
#pragma unroll
            for (int r = 0; r < 16; ++r) acc[i][j][r] = 0.f;

#define ISSUE(u) { \
    u8* lb = (u8*)smem + ((u) % 3) * 32768; \
    const int ko = (u) * 64; \
    gld16(gA[0] + ko, lb + lo[0]); \
    gld16(gA[0] + dBA + ko, lb + 16384 + lo[0]); \
    gld16(gA[1] + ko, lb + lo[1]); \
    gld16(gA[1] + dBA + ko, lb + 16384 + lo[1]); }

#define LOADFRAG(dst, off) { \
    int4 L_ = *(const int4*)(base + (off)); \
    int4 H_ = *(const int4*)(base + ((off) ^ 16)); \
    dst = (i32x8){L_.x, L_.y, L_.z, L_.w, H_.x, H_.y, H_.z, H_.w}; }

    ISSUE(0); ISSUE(1);                    // 8 loads in flight

#pragma unroll
    for (int kt = 0; kt < 14; ++kt) {
        if (kt < 12) {
            ISSUE(kt + 2);                              // depth-2 prefetch
            __builtin_amdgcn_s_waitcnt(0x0F78);         // vmcnt(8): kt landed
        } else if (kt == 12) {
            __builtin_amdgcn_s_waitcnt(0x0F74);         // vmcnt(4)
        } else {
            __builtin_amdgcn_s_waitcnt(0x0F70);         // vmcnt(0)
        }
        __builtin_amdgcn_s_barrier();                   // all waves staged kt

        const char* base = smem + (kt % 3) * 32768;
        i32x8 b0, b1;
        LOADFRAG(b0, boff);
        LOADFRAG(b1, boff + 2048);
#pragma unroll
        for (int ih = 0; ih < 2; ++ih) {
            const int i0 = ih * 2;
            i32x8 a0, a1;
            LOADFRAG(a0, aoff + i0 * 2048);
            LOADFRAG(a1, aoff + (i0 + 1) * 2048);
            acc[i0][0] = __builtin_amdgcn_mfma_scale_f32_32x32x64_f8f6f4(
                a0, b0, acc[i0][0], 0, 0, 0, 127, 0, 127);
            acc[i0][1] = __builtin_amdgcn_mfma_scale_f32_32x32x64_f8f6f4(
                a0, b1, acc[i0][1], 0, 0, 0, 127, 0, 127);
            acc[i0 + 1][0] = __builtin_amdgcn_mfma_scale_f32_32x32x64_f8f6f4(
                a1, b0, acc[i0 + 1][0], 0, 0, 0, 127, 0, 127);
            acc[i0 + 1][1] = __builtin_amdgcn_mfma_scale_f32_32x32x64_f8f6f4(
                a1, b1, acc[i0 + 1][1], 0, 0, 0, 127, 0, 127);
            __builtin_amdgcn_sched_barrier(0);  // keep phase-2 a-reads below
        }

        __builtin_amdgcn_s_barrier();                   // readers of slot done
    }
#undef LOADFRAG
#undef ISSUE

    // ---- epilogue ----
    const float vn0 = vnorm[bCol * 256 + waveCol * 64 + lr];
    const float vn1 = vnorm[bCol * 256 + waveCol * 64 + 32 + lr];
    __syncthreads();   // drain before partials overlay the ring

    // j-combine (2 cols) then pair-combine with lane^16 (4 cols) -> write.
#pragma unroll
    for (int i = 0; i < 4; ++i) {
#pragma unroll
        for (int r = 0; r < 16; ++r) {
            float w0 = acc[i][0][r] - 0.5f * vn0;
            float w1 = acc[i][1][r] - 0.5f * vn1;
            float m = fmaxf(w0, w1);
            float s = __expf(w0 - m) + __expf(w1 - m);
            float mo = __shfl_xor(m, 16);
            float so = __shfl_xor(s, 16);
            float M = fmaxf(m, mo);
            s = s * __expf(m - M) + so * __expf(mo - M);
            if (lr < 16) {
                const int rin = (r & 3) + 8 * (r >> 2) + 4 * h;
                part[(waveRow * 128 + i * 32 + rin) * 64 + (waveCol * 16 + lr)] =
                    make_float2(M, s);
            }
        }
    }
    __syncthreads();
    {
        const int row = tid >> 1, half = tid & 1;
        const float2* p = part + row * 64 + half * 32;
        float m = -3.4e38f;
#pragma unroll 8
        for (int q = 0; q < 32; ++q) m = fmaxf(m, p[(q + row) & 31].x);
        float s = 0.f;
#pragma unroll 8
        for (int q = 0; q < 32; ++q) { float2 v = p[(q + row) & 31]; s += v.y * __expf(v.x - m); }
        float mo = __shfl_xor(m, 1);
        float so = __shfl_xor(s, 1);
        float M = fmaxf(m, mo);
        s = s * __expf(m - M) + so * __expf(mo - M);
        if (half == 0) {
            size_t grow = (size_t)(bRow * 256 + row);
            pmax[grow * 16 + bCol] = M;
            psum[grow * 16 + bCol] = s;
        }
    }
}

// --------------- k_final: combine 16 partials + row constants --------------
__global__ __launch_bounds__(256) void k_final(const float* __restrict__ pmax,
                                               const float* __restrict__ psum,
                                               const float* __restrict__ norm,
                                               const float* __restrict__ stdv,
                                               float* __restrict__ out) {
    __shared__ float wsum[4];
    const int t = threadIdx.x;
    float ls = 0.f;
    for (int d = t; d < D_DIM; d += 256) ls += logf(stdv[d]);
    for (int m = 32; m; m >>= 1) ls += __shfl_xor(ls, m);
    if ((t & 63) == 0) wsum[t >> 6] = ls;
    __syncthreads();
    const float logc = -0.5f * (float)D_DIM * LOG2PI - (wsum[0] + wsum[1] + wsum[2] + wsum[3]);

    const int n = blockIdx.x * 256 + t;
    const float* pm = pmax + (size_t)n * 16;
    const float* ps = psum + (size_t)n * 16;
    float gm = pm[0];
#pragma unroll
    for (int c = 1; c < 16; ++c) gm = fmaxf(gm, pm[c]);
    float S = 0.f;
#pragma unroll
    for (int c = 0; c < 16; ++c) S += ps[c] * __expf(pm[c] - gm);
    out[n] = gm + logf(S) - 0.5f * norm[n] + logc - LOGM;
}

// ---------------------------------------------------------------------------
extern "C" void kernel_launch(void* const* d_in, const int* in_sizes, int n_in,
                              void* d_out, int out_size, void* d_ws, size_t ws_size,
                              hipStream_t stream) {
    const float* samples = (const float*)d_in[0];  // 8192*784
    const float* x       = (const float*)d_in[1];  // 4096*784
    const float* stdv    = (const float*)d_in[2];  // 784
    float* out = (float*)d_out;                    // 8192

    char* ws = (char*)d_ws;
    // U fp8 (8192*896) | V fp8 (4096*896) | norm (12288 f32) | pmax | psum
    u8*    U    = (u8*)ws;                        //  7,340,032 B
    u8*    V    = (u8*)(ws + 7340032);            //  3,670,016 B
    float* norm = (float*)(ws + 11010048);        //     49,152 B
    float* pmax = (float*)(ws + 11059200);        //    524,288 B
    float* psum = (float*)(ws + 11583488);        //    524,288 B  (total ~12.1 MB)

    k_prep<<<(N_ROWS + M_ROWS) / 8, 256, 0, stream>>>(samples, x, stdv, U, norm);
    k_gemm<<<dim3(M_ROWS / 256, N_ROWS / 256), 512, 0, stream>>>(U, V, norm + N_ROWS, pmax, psum);
    k_final<<<N_ROWS / 256, 256, 0, stream>>>(pmax, psum, norm, stdv, out);
}

// Round 5
// 231.600 us; speedup vs baseline: 1.2424x; 1.1257x over previous
//
#include <hip/hip_runtime.h>
#include <cstdint>
#include <cstddef>

// ---------------------------------------------------------------------------
// logsumexp_m[ -0.5*||(s_n - x_m)/std||^2 ] + logc - log M   (N=8192,M=4096,D=784)
// R8: kill the spill by killing the 256-VGPR cap: 256-thread block (4 waves,
// 1 wave/SIMD -> 512-VGPR budget), wave tile 128x128 (acc = 16 x f32x16 =
// 256 regs, ~340 live total, no spill by construction). 32x32x64 MX-fp8.
// kt64 ring of 3 x 32KB slots (96KB), counted vmcnt depth-2 (16 in flight,
// vmcnt 16->8->0), 2 barriers/kt, 14 kt steps. R2 slot swizzle kept.
// No sched_barrier/setprio: at 1 wave/SIMD we WANT the compiler to hoist
// ds_reads over the 16 independent MFMAs (ILP is the only latency cover).
// Epilogue: j-combine + xor16 -> [256][32] float2 overlay (64KB), rotated
// scan, 16 partials/row (k_final unchanged).
// ---------------------------------------------------------------------------

#define N_ROWS 8192
#define M_ROWS 4096
#define D_DIM  784
#define KPB    896        // K bytes per row (fp8), padded 784 -> 14*64
#define LOG2PI 1.8378770664093453f
#define LOGM   8.317766166719343f   // log(4096)

typedef unsigned char u8;
typedef __attribute__((ext_vector_type(8)))  int   i32x8;
typedef __attribute__((ext_vector_type(16))) float f32x16;

__device__ __forceinline__ void gld16(const u8* g, u8* l) {
    __builtin_amdgcn_global_load_lds(
        (__attribute__((address_space(1))) void*)(void*)g,
        (__attribute__((address_space(3))) void*)l, 16, 0, 0);
}

// ------------- k_prep: scale, fp8-round, row norms (wave x 2 rows) ---------
__global__ __launch_bounds__(256) void k_prep(const float* __restrict__ samples,
                                              const float* __restrict__ x,
                                              const float* __restrict__ stdv,
                                              u8* __restrict__ dst,
                                              float* __restrict__ norm) {
    const int wid = threadIdx.x >> 6, lane = threadIdx.x & 63;
    const int row0 = blockIdx.x * 8 + wid * 2;

    float4 rstd[4];
#pragma unroll
    for (int i = 0; i < 4; ++i) {
        int c = lane + 64 * i;
        rstd[i] = make_float4(1.f, 1.f, 1.f, 1.f);
        if (c < 196) {
            float4 d = ((const float4*)stdv)[c];
            rstd[i] = make_float4(1.f / d.x, 1.f / d.y, 1.f / d.z, 1.f / d.w);
        }
    }

#pragma unroll
    for (int rr = 0; rr < 2; ++rr) {
        const int row = row0 + rr;
        const float* src = (row < N_ROWS) ? samples + (size_t)row * D_DIM
                                          : x + (size_t)(row - N_ROWS) * D_DIM;
        unsigned* drow = (unsigned*)(dst + (size_t)row * KPB);
        float sq = 0.f;
#pragma unroll
        for (int i = 0; i < 4; ++i) {
            const int c = lane + 64 * i;       // u32 chunk (4 fp8)
            if (c < 224) {                     // 224*4 = 896 = KPB
                unsigned p = 0;
                if (c < 196) {                 // 196*4 = 784 = D
                    float4 s = ((const float4*)src)[c];
                    float ux = s.x * rstd[i].x, uy = s.y * rstd[i].y;
                    float uz = s.z * rstd[i].z, uw = s.w * rstd[i].w;
                    p = __builtin_amdgcn_cvt_pk_fp8_f32(ux, uy, 0, false);
                    p = __builtin_amdgcn_cvt_pk_fp8_f32(uz, uw, p, true);
                    float r0 = __builtin_amdgcn_cvt_f32_fp8(p, 0);
                    float r1 = __builtin_amdgcn_cvt_f32_fp8(p, 1);
                    float r2 = __builtin_amdgcn_cvt_f32_fp8(p, 2);
                    float r3 = __builtin_amdgcn_cvt_f32_fp8(p, 3);
                    sq += r0 * r0 + r1 * r1 + r2 * r2 + r3 * r3;  // norm of ROUNDED
                }
                drow[c] = p;
            }
        }
        for (int m = 32; m; m >>= 1) sq += __shfl_xor(sq, m);
        if (lane == 0) norm[row] = sq;
    }
}

// ---------------- k_gemm: 256x256 tile, 4 waves of 128x128, kt64 ring ------
// LDS slots s=0..2 at s*32768: A 256x64B at +0 (16KB), B 256x64B at +16384.
// Slot chunk c of row r holds global K-granule c ^ ((r>>1)&3)  (R2 swizzle).
// 32x32x64 frag: lane l: row = l&31, k-bytes [32*(l>>5), +32) -> chunks
// {(2h)^key, ^1} -> b128 at addr and addr^16 (key = ((row>>1)&3)).
// C/D: col = lane&31, row-in-32 = (reg&3) + 8*(reg>>2) + 4*(lane>>5).
// Waves 2x2: waveRow = wid>>1 (128 rows), waveCol = wid&1 (128 cols).
__global__ __launch_bounds__(256, 1) void k_gemm(const u8* __restrict__ U,
                                                 const u8* __restrict__ V,
                                                 const float* __restrict__ vnorm,
                                                 float* __restrict__ pmax,
                                                 float* __restrict__ psum) {
    __shared__ __align__(16) char smem[98304];   // 3 x 32KB ring; epi overlay
    float2* part = (float2*)smem;                // [256][32] epilogue partials

    const int tid = threadIdx.x;
    const int lane = tid & 63;
    const int wid = tid >> 6;              // 0..3
    const int waveRow = wid >> 1;          // 0..1 (128-row half)
    const int waveCol = wid & 1;           // 0..1 (128-col half)
    const int bCol = blockIdx.x;           // 0..15
    const int bRow = blockIdx.y;           // 0..31
    const int lr = lane & 31, h = lane >> 5;

    // ---- staging: per kt64 slot, 4 A + 4 B gld16/thread. Inst q: wave wid
    // covers rows wid*64 + q*16 + (lane>>2), chunk lane&3 (pre-swizzled src).
    const int r4 = lane >> 2;
    const int gc = (lane & 3) ^ ((lane >> 3) & 3);
    const u8* gA[4]; int lo[4];
#pragma unroll
    for (int q = 0; q < 4; ++q) {
        const int row = wid * 64 + q * 16 + r4;     // 0..255
        gA[q] = U + (size_t)(bRow * 256 + row) * KPB + gc * 16;
        lo[q] = wid * 4096 + q * 1024;              // wave-uniform LDS offset
    }
    const ptrdiff_t dBA = (V - U) +
        ((ptrdiff_t)bCol * 256 - (ptrdiff_t)bRow * 256) * (ptrdiff_t)KPB;

    // ---- frag-read offsets
    const int key = (lr >> 1) & 3;
    const int slotL = (2 * h) ^ key;
    const int aoff = (waveRow * 128 + lr) * 64 + slotL * 16;           // +i*2048
    const int boff = 16384 + (waveCol * 128 + lr) * 64 + slotL * 16;   // +j*2048

    f32x16 acc[4][4];
#pragma unroll
    for (int i = 0; i < 4; ++i)
#pragma unroll
        for (int j = 0; j < 4; ++j)
#pragma unroll
            for (int r = 0; r < 16; ++r) acc[i][j][r] = 0.f;

#define ISSUE(u) { \
    u8* lb = (u8*)smem + ((u) % 3) * 32768; \
    const int ko = (u) * 64; \
    gld16(gA[0] + ko, lb + lo[0]); \
    gld16(gA[0] + dBA + ko, lb + 16384 + lo[0]); \
    gld16(gA[1] + ko, lb + lo[1]); \
    gld16(gA[1] + dBA + ko, lb + 16384 + lo[1]); \
    gld16(gA[2] + ko, lb + lo[2]); \
    gld16(gA[2] + dBA + ko, lb + 16384 + lo[2]); \
    gld16(gA[3] + ko, lb + lo[3]); \
    gld16(gA[3] + dBA + ko, lb + 16384 + lo[3]); }

#define LOADFRAG(dst, off) { \
    int4 L_ = *(const int4*)(base + (off)); \
    int4 H_ = *(const int4*)(base + ((off) ^ 16)); \
    dst = (i32x8){L_.x, L_.y, L_.z, L_.w, H_.x, H_.y, H_.z, H_.w}; }

    ISSUE(0); ISSUE(1);                    // 16 loads in flight (depth-2)

#pragma unroll
    for (int kt = 0; kt < 14; ++kt) {
        if (kt < 12) {
            ISSUE(kt + 2);                              // -> 24 outstanding
            __builtin_amdgcn_s_waitcnt(0x4F70);         // vmcnt(16): kt landed
        } else if (kt == 12) {
            __builtin_amdgcn_s_waitcnt(0x0F78);         // vmcnt(8)
        } else {
            __builtin_amdgcn_s_waitcnt(0x0F70);         // vmcnt(0)
        }
        __builtin_amdgcn_s_barrier();                   // all waves staged kt

        const char* base = smem + (kt % 3) * 32768;
        i32x8 b0, b1, b2, b3;
        LOADFRAG(b0, boff);
        LOADFRAG(b1, boff + 2048);
        LOADFRAG(b2, boff + 2 * 2048);
        LOADFRAG(b3, boff + 3 * 2048);
#pragma unroll
        for (int i = 0; i < 4; ++i) {
            i32x8 ai;
            LOADFRAG(ai, aoff + i * 2048);
            acc[i][0] = __builtin_amdgcn_mfma_scale_f32_32x32x64_f8f6f4(
                ai, b0, acc[i][0], 0, 0, 0, 127, 0, 127);
            acc[i][1] = __builtin_amdgcn_mfma_scale_f32_32x32x64_f8f6f4(
                ai, b1, acc[i][1], 0, 0, 0, 127, 0, 127);
            acc[i][2] = __builtin_amdgcn_mfma_scale_f32_32x32x64_f8f6f4(
                ai, b2, acc[i][2], 0, 0, 0, 127, 0, 127);
            acc[i][3] = __builtin_amdgcn_mfma_scale_f32_32x32x64_f8f6f4(
                ai, b3, acc[i][3], 0, 0, 0, 127, 0, 127);
        }

        __builtin_amdgcn_s_barrier();                   // readers of slot done
    }
#undef LOADFRAG
#undef ISSUE

    // ---- epilogue ----
    float vn[4];
#pragma unroll
    for (int j = 0; j < 4; ++j)
        vn[j] = vnorm[bCol * 256 + waveCol * 128 + j * 32 + lr];
    __syncthreads();   // drain before partials overlay the ring

    // j-combine (4 cols: lr + 32j) then pair-combine with lane^16 (8 cols).
#pragma unroll
    for (int i = 0; i < 4; ++i) {
#pragma unroll
        for (int r = 0; r < 16; ++r) {
            float w0 = acc[i][0][r] - 0.5f * vn[0];
            float w1 = acc[i][1][r] - 0.5f * vn[1];
            float w2 = acc[i][2][r] - 0.5f * vn[2];
            float w3 = acc[i][3][r] - 0.5f * vn[3];
            float m = fmaxf(fmaxf(w0, w1), fmaxf(w2, w3));
            float s = __expf(w0 - m) + __expf(w1 - m) + __expf(w2 - m) + __expf(w3 - m);
            float mo = __shfl_xor(m, 16);
            float so = __shfl_xor(s, 16);
            float M = fmaxf(m, mo);
            s = s * __expf(m - M) + so * __expf(mo - M);
            if (lr < 16) {
                const int rin = (r & 3) + 8 * (r >> 2) + 4 * h;
                part[(waveRow * 128 + i * 32 + rin) * 32 + (waveCol * 16 + lr)] =
                    make_float2(M, s);
            }
        }
    }
    __syncthreads();
    {
        const int row = tid;                       // 0..255
        const float2* p = part + row * 32;
        float m = -3.4e38f;
#pragma unroll 8
        for (int q = 0; q < 32; ++q) m = fmaxf(m, p[(q + row) & 31].x);
        float s = 0.f;
#pragma unroll 8
        for (int q = 0; q < 32; ++q) { float2 v = p[(q + row) & 31]; s += v.y * __expf(v.x - m); }
        size_t grow = (size_t)(bRow * 256 + row);
        pmax[grow * 16 + bCol] = m;
        psum[grow * 16 + bCol] = s;
    }
}

// --------------- k_final: combine 16 partials + row constants --------------
__global__ __launch_bounds__(256) void k_final(const float* __restrict__ pmax,
                                               const float* __restrict__ psum,
                                               const float* __restrict__ norm,
                                               const float* __restrict__ stdv,
                                               float* __restrict__ out) {
    __shared__ float wsum[4];
    const int t = threadIdx.x;
    float ls = 0.f;
    for (int d = t; d < D_DIM; d += 256) ls += logf(stdv[d]);
    for (int m = 32; m; m >>= 1) ls += __shfl_xor(ls, m);
    if ((t & 63) == 0) wsum[t >> 6] = ls;
    __syncthreads();
    const float logc = -0.5f * (float)D_DIM * LOG2PI - (wsum[0] + wsum[1] + wsum[2] + wsum[3]);

    const int n = blockIdx.x * 256 + t;
    const float* pm = pmax + (size_t)n * 16;
    const float* ps = psum + (size_t)n * 16;
    float gm = pm[0];
#pragma unroll
    for (int c = 1; c < 16; ++c) gm = fmaxf(gm, pm[c]);
    float S = 0.f;
#pragma unroll
    for (int c = 0; c < 16; ++c) S += ps[c] * __expf(pm[c] - gm);
    out[n] = gm + logf(S) - 0.5f * norm[n] + logc - LOGM;
}

// ---------------------------------------------------------------------------
extern "C" void kernel_launch(void* const* d_in, const int* in_sizes, int n_in,
                              void* d_out, int out_size, void* d_ws, size_t ws_size,
                              hipStream_t stream) {
    const float* samples = (const float*)d_in[0];  // 8192*784
    const float* x       = (const float*)d_in[1];  // 4096*784
    const float* stdv    = (const float*)d_in[2];  // 784
    float* out = (float*)d_out;                    // 8192

    char* ws = (char*)d_ws;
    // U fp8 (8192*896) | V fp8 (4096*896) | norm (12288 f32) | pmax | psum
    u8*    U    = (u8*)ws;                        //  7,340,032 B
    u8*    V    = (u8*)(ws + 7340032);            //  3,670,016 B
    float* norm = (float*)(ws + 11010048);        //     49,152 B
    float* pmax = (float*)(ws + 11059200);        //    524,288 B
    float* psum = (float*)(ws + 11583488);        //    524,288 B  (total ~12.1 MB)

    k_prep<<<(N_ROWS + M_ROWS) / 8, 256, 0, stream>>>(samples, x, stdv, U, norm);
    k_gemm<<<dim3(M_ROWS / 256, N_ROWS / 256), 256, 0, stream>>>(U, V, norm + N_ROWS, pmax, psum);
    k_final<<<N_ROWS / 256, 256, 0, stream>>>(pmax, psum, norm, stdv, out);
}

// Round 6
// 135.933 us; speedup vs baseline: 2.1168x; 1.7038x over previous
//
#include <hip/hip_runtime.h>
#include <cstdint>
#include <cstddef>

// ---------------------------------------------------------------------------
// logsumexp_m[ -0.5*||(s_n - x_m)/std||^2 ] + logc - log M   (N=8192,M=4096,D=784)
// R9: f32x4-accumulator rule (R5 proved 4-aligned acc packs into AGPRs;
// f32x16 spilled in R6/R7/R8). 256x256 tile, 512 thr / 8 waves, wave=128x64,
// 16x16x128 MX-fp8 MFMA (acc f32x4[8][4] = 128 AGPRs). kt64 ring of
// 4 x 32KB slots (128KB); tile T = slot pair {2T,2T+1} @ (T&1)*65536.
// R4's 2-barrier/K-step schedule, counted vmcnt(8) (never 0 mid-loop),
// depth-2 tile prefetch, 7 K-steps. R2 conflict-free slot swizzle
// (chunk c of row r holds granule c^((r>>1)&3); pre-swizzled global src,
// linear gld_lds dest, swizzled frag read — R4-verified formulas).
// Epilogue: j-combine -> [256][64] float2 overlay (exactly 128KB), rotated
// scan, 16 partials/row (k_final unchanged).
// ---------------------------------------------------------------------------

#define N_ROWS 8192
#define M_ROWS 4096
#define D_DIM  784
#define KPB    896        // K bytes per row (fp8), padded 784 -> 14*64
#define LOG2PI 1.8378770664093453f
#define LOGM   8.317766166719343f   // log(4096)

typedef unsigned char u8;
typedef __attribute__((ext_vector_type(8))) int   i32x8;
typedef __attribute__((ext_vector_type(4))) float f32x4;

__device__ __forceinline__ void gld16(const u8* g, u8* l) {
    __builtin_amdgcn_global_load_lds(
        (__attribute__((address_space(1))) void*)(void*)g,
        (__attribute__((address_space(3))) void*)l, 16, 0, 0);
}

// ------------- k_prep: scale, fp8-round, row norms (wave x 2 rows) ---------
__global__ __launch_bounds__(256) void k_prep(const float* __restrict__ samples,
                                              const float* __restrict__ x,
                                              const float* __restrict__ stdv,
                                              u8* __restrict__ dst,
                                              float* __restrict__ norm) {
    const int wid = threadIdx.x >> 6, lane = threadIdx.x & 63;
    const int row0 = blockIdx.x * 8 + wid * 2;

    float4 rstd[4];
#pragma unroll
    for (int i = 0; i < 4; ++i) {
        int c = lane + 64 * i;
        rstd[i] = make_float4(1.f, 1.f, 1.f, 1.f);
        if (c < 196) {
            float4 d = ((const float4*)stdv)[c];
            rstd[i] = make_float4(1.f / d.x, 1.f / d.y, 1.f / d.z, 1.f / d.w);
        }
    }

#pragma unroll
    for (int rr = 0; rr < 2; ++rr) {
        const int row = row0 + rr;
        const float* src = (row < N_ROWS) ? samples + (size_t)row * D_DIM
                                          : x + (size_t)(row - N_ROWS) * D_DIM;
        unsigned* drow = (unsigned*)(dst + (size_t)row * KPB);
        float sq = 0.f;
#pragma unroll
        for (int i = 0; i < 4; ++i) {
            const int c = lane + 64 * i;       // u32 chunk (4 fp8)
            if (c < 224) {                     // 224*4 = 896 = KPB
                unsigned p = 0;
                if (c < 196) {                 // 196*4 = 784 = D
                    float4 s = ((const float4*)src)[c];
                    float ux = s.x * rstd[i].x, uy = s.y * rstd[i].y;
                    float uz = s.z * rstd[i].z, uw = s.w * rstd[i].w;
                    p = __builtin_amdgcn_cvt_pk_fp8_f32(ux, uy, 0, false);
                    p = __builtin_amdgcn_cvt_pk_fp8_f32(uz, uw, p, true);
                    float r0 = __builtin_amdgcn_cvt_f32_fp8(p, 0);
                    float r1 = __builtin_amdgcn_cvt_f32_fp8(p, 1);
                    float r2 = __builtin_amdgcn_cvt_f32_fp8(p, 2);
                    float r3 = __builtin_amdgcn_cvt_f32_fp8(p, 3);
                    sq += r0 * r0 + r1 * r1 + r2 * r2 + r3 * r3;  // norm of ROUNDED
                }
                drow[c] = p;
            }
        }
        for (int m = 32; m; m >>= 1) sq += __shfl_xor(sq, m);
        if (lane == 0) norm[row] = sq;
    }
}

// ---------------- k_gemm: 256x256 tile, 16x16x128, kt64 ring of 4 ----------
// LDS slot u&3 at (u&3)*32768: A 256x64B @ +0, B 256x64B @ +16384.
// Slot chunk c of row r holds global K-granule c ^ ((r>>1)&3).
// 16x16x128 frag: lane l: row = l&15, k-bytes [32*(l>>4), +32) -> sub-slot
// (g>>1)*32768, chunks {(2*(g&1))^key, ^1} -> b128 at addr and addr^16,
// key = ((l&15)>>1)&3.  C/D: col = lane&15, row-in-16 = (lane>>4)*4 + reg.
// Waves: waveRow = wid>>2 (128-row half), waveCol = wid&3 (64-col quarter).
__global__ __launch_bounds__(512, 2) void k_gemm(const u8* __restrict__ U,
                                                 const u8* __restrict__ V,
                                                 const float* __restrict__ vnorm,
                                                 float* __restrict__ pmax,
                                                 float* __restrict__ psum) {
    __shared__ __align__(16) char smem[131072];  // 4x32KB ring; epi overlay
    float2* part = (float2*)smem;                // [256][64] epilogue partials

    const int tid = threadIdx.x;
    const int lane = tid & 63;
    const int wid = tid >> 6;              // 0..7
    const int waveRow = wid >> 2;          // 0..1 (128-row half)
    const int waveCol = wid & 3;           // 0..3 (64-col quarter)
    const int bCol = blockIdx.x;           // 0..15
    const int bRow = blockIdx.y;           // 0..31
    const int g = lane >> 4, rl = lane & 15;

    // ---- staging: per kt64 slot, 2 A + 2 B gld16/thread. Inst q: wave wid
    // covers rows wid*32 + q*16 + (lane>>2), chunk lane&3 (pre-swizzled src).
    const int r4 = lane >> 2;
    const int gc = (lane & 3) ^ ((lane >> 3) & 3);
    const u8* gA[2]; int lo[2];
#pragma unroll
    for (int q = 0; q < 2; ++q) {
        const int row = wid * 32 + q * 16 + r4;     // 0..255
        gA[q] = U + (size_t)(bRow * 256 + row) * KPB + gc * 16;
        lo[q] = wid * 2048 + q * 1024;              // wave-uniform LDS offset
    }
    const ptrdiff_t dBA = (V - U) +
        ((ptrdiff_t)bCol * 256 - (ptrdiff_t)bRow * 256) * (ptrdiff_t)KPB;

    // ---- frag-read offsets (relative to tile base (T&1)*65536)
    const int key = (rl >> 1) & 3;
    const int slotL = (2 * (g & 1)) ^ key;
    const int aoff = (g >> 1) * 32768 + (waveRow * 128 + rl) * 64 + slotL * 16;         // +i*1024
    const int boff = (g >> 1) * 32768 + 16384 + (waveCol * 64 + rl) * 64 + slotL * 16;  // +j*1024

    f32x4 acc[8][4];
#pragma unroll
    for (int i = 0; i < 8; ++i)
#pragma unroll
        for (int j = 0; j < 4; ++j) acc[i][j] = (f32x4){0.f, 0.f, 0.f, 0.f};

#define ISSUE(u) { \
    u8* lb = (u8*)smem + ((u) & 3) * 32768; \
    const int ko = (u) * 64; \
    gld16(gA[0] + ko, lb + lo[0]); \
    gld16(gA[0] + dBA + ko, lb + 16384 + lo[0]); \
    gld16(gA[1] + ko, lb + lo[1]); \
    gld16(gA[1] + dBA + ko, lb + 16384 + lo[1]); }

#define ISSUE_TILE(T) { ISSUE(2*(T)); ISSUE(2*(T)+1); }

#define LOADFRAG(dst, off) { \
    int4 L_ = *(const int4*)(base + (off)); \
    int4 H_ = *(const int4*)(base + ((off) ^ 16)); \
    dst = (i32x8){L_.x, L_.y, L_.z, L_.w, H_.x, H_.y, H_.z, H_.w}; }

    ISSUE_TILE(0); ISSUE_TILE(1);          // 16 loads in flight (depth-2)

#pragma unroll
    for (int T = 0; T < 7; ++T) {
        if (T < 6) __builtin_amdgcn_s_waitcnt(0x0F78);  // vmcnt(8): tile T landed
        else       __builtin_amdgcn_s_waitcnt(0x0F70);  // vmcnt(0): last tile
        __builtin_amdgcn_s_barrier();                   // all waves staged T

        const char* base = smem + (T & 1) * 65536;
        i32x8 b0, b1, b2, b3;
        LOADFRAG(b0, boff);
        LOADFRAG(b1, boff + 1024);
        LOADFRAG(b2, boff + 2 * 1024);
        LOADFRAG(b3, boff + 3 * 1024);
#pragma unroll
        for (int i = 0; i < 8; ++i) {
            i32x8 ai;
            LOADFRAG(ai, aoff + i * 1024);
            acc[i][0] = __builtin_amdgcn_mfma_scale_f32_16x16x128_f8f6f4(
                ai, b0, acc[i][0], 0, 0, 0, 127, 0, 127);
            acc[i][1] = __builtin_amdgcn_mfma_scale_f32_16x16x128_f8f6f4(
                ai, b1, acc[i][1], 0, 0, 0, 127, 0, 127);
            acc[i][2] = __builtin_amdgcn_mfma_scale_f32_16x16x128_f8f6f4(
                ai, b2, acc[i][2], 0, 0, 0, 127, 0, 127);
            acc[i][3] = __builtin_amdgcn_mfma_scale_f32_16x16x128_f8f6f4(
                ai, b3, acc[i][3], 0, 0, 0, 127, 0, 127);
        }

        __builtin_amdgcn_s_barrier();                   // readers of T done
        if (T < 5) ISSUE_TILE(T + 2);                   // slots {2T,2T+1} free
    }
#undef LOADFRAG
#undef ISSUE_TILE
#undef ISSUE

    // ---- epilogue: w = dot - 0.5*vn; j-combine (4 cols) -> [256][64] ----
    float vn[4];
#pragma unroll
    for (int j = 0; j < 4; ++j) vn[j] = vnorm[bCol * 256 + waveCol * 64 + j * 16 + rl];
    __syncthreads();   // drain before partials overlay the ring

    const int prow0 = waveRow * 128 + g * 4;
    const int pc = waveCol * 16 + rl;
#pragma unroll
    for (int i = 0; i < 8; ++i) {
#pragma unroll
        for (int r = 0; r < 4; ++r) {
            float w0 = acc[i][0][r] - 0.5f * vn[0];
            float w1 = acc[i][1][r] - 0.5f * vn[1];
            float w2 = acc[i][2][r] - 0.5f * vn[2];
            float w3 = acc[i][3][r] - 0.5f * vn[3];
            float m = fmaxf(fmaxf(w0, w1), fmaxf(w2, w3));
            float s = __expf(w0 - m) + __expf(w1 - m) + __expf(w2 - m) + __expf(w3 - m);
            part[(prow0 + i * 16 + r) * 64 + pc] = make_float2(m, s);
        }
    }
    __syncthreads();
    if (tid < 256) {
        const int row = tid;                       // 0..255
        const float2* p = part + row * 64;
        const int rot = row & 63;                  // rotated start: min-conflict
        float m = -3.4e38f;
#pragma unroll 8
        for (int q = 0; q < 64; ++q) m = fmaxf(m, p[(q + rot) & 63].x);
        float s = 0.f;
#pragma unroll 8
        for (int q = 0; q < 64; ++q) { float2 v = p[(q + rot) & 63]; s += v.y * __expf(v.x - m); }
        size_t grow = (size_t)(bRow * 256 + row);
        pmax[grow * 16 + bCol] = m;
        psum[grow * 16 + bCol] = s;
    }
}

// --------------- k_final: combine 16 partials + row constants --------------
__global__ __launch_bounds__(256) void k_final(const float* __restrict__ pmax,
                                               const float* __restrict__ psum,
                                               const float* __restrict__ norm,
                                               const float* __restrict__ stdv,
                                               float* __restrict__ out) {
    __shared__ float wsum[4];
    const int t = threadIdx.x;
    float ls = 0.f;
    for (int d = t; d < D_DIM; d += 256) ls += logf(stdv[d]);
    for (int m = 32; m; m >>= 1) ls += __shfl_xor(ls, m);
    if ((t & 63) == 0) wsum[t >> 6] = ls;
    __syncthreads();
    const float logc = -0.5f * (float)D_DIM * LOG2PI - (wsum[0] + wsum[1] + wsum[2] + wsum[3]);

    const int n = blockIdx.x * 256 + t;
    const float* pm = pmax + (size_t)n * 16;
    const float* ps = psum + (size_t)n * 16;
    float gm = pm[0];
#pragma unroll
    for (int c = 1; c < 16; ++c) gm = fmaxf(gm, pm[c]);
    float S = 0.f;
#pragma unroll
    for (int c = 0; c < 16; ++c) S += ps[c] * __expf(pm[c] - gm);
    out[n] = gm + logf(S) - 0.5f * norm[n] + logc - LOGM;
}

// ---------------------------------------------------------------------------
extern "C" void kernel_launch(void* const* d_in, const int* in_sizes, int n_in,
                              void* d_out, int out_size, void* d_ws, size_t ws_size,
                              hipStream_t stream) {
    const float* samples = (const float*)d_in[0];  // 8192*784
    const float* x       = (const float*)d_in[1];  // 4096*784
    const float* stdv    = (const float*)d_in[2];  // 784
    float* out = (float*)d_out;                    // 8192

    char* ws = (char*)d_ws;
    // U fp8 (8192*896) | V fp8 (4096*896) | norm (12288 f32) | pmax | psum
    u8*    U    = (u8*)ws;                        //  7,340,032 B
    u8*    V    = (u8*)(ws + 7340032);            //  3,670,016 B
    float* norm = (float*)(ws + 11010048);        //     49,152 B
    float* pmax = (float*)(ws + 11059200);        //    524,288 B
    float* psum = (float*)(ws + 11583488);        //    524,288 B  (total ~12.1 MB)

    k_prep<<<(N_ROWS + M_ROWS) / 8, 256, 0, stream>>>(samples, x, stdv, U, norm);
    k_gemm<<<dim3(M_ROWS / 256, N_ROWS / 256), 512, 0, stream>>>(U, V, norm + N_ROWS, pmax, psum);
    k_final<<<N_ROWS / 256, 256, 0, stream>>>(pmax, psum, norm, stdv, out);
}

// Round 8
// 135.817 us; speedup vs baseline: 2.1186x; 1.0009x over previous
//
#include <hip/hip_runtime.h>
#include <cstdint>
#include <cstddef>

// ---------------------------------------------------------------------------
// logsumexp_m[ -0.5*||(s_n - x_m)/std||^2 ] + logc - log M   (N=8192,M=4096,D=784)
// R11: R9's proven ring discipline (4x32KB kt64 slots = 2 tiles; depth-2 tile
// prefetch; ISSUE(T+2) only after the barrier ending reads of T) restructured
// to ONE barrier per tile, tail-wait form:
//   compute T; vmcnt(0) [own T+1 loads only, issued ~2200cyc ago => ~free];
//   barrier [publishes T+1 + proves reads of T done]; issue T+2.
// 8 sync points/round vs R9's 14; wait moved to after compute.
// R10's ring-overflow bug (4 tiles staged into the 2-tile ring) is NOT
// repeated: prologue stages exactly tiles {0,1}.
// Kept from R10 (re-verified bijections, not implicated in the failure):
// XCD-bijective block swizzle; transposed pmax/psum [bCol][row]; setprio.
// Geometry: 256x256 tile, 512 thr / 8 waves, wave=128x64, 16x16x128 MX-fp8,
// f32x4 acc (no-spill rule), R2 conflict-free slot swizzle (R9-verified).
// ---------------------------------------------------------------------------

#define N_ROWS 8192
#define M_ROWS 4096
#define D_DIM  784
#define KPB    896        // K bytes per row (fp8), padded 784 -> 14*64
#define LOG2PI 1.8378770664093453f
#define LOGM   8.317766166719343f   // log(4096)

typedef unsigned char u8;
typedef __attribute__((ext_vector_type(8))) int   i32x8;
typedef __attribute__((ext_vector_type(4))) float f32x4;

__device__ __forceinline__ void gld16(const u8* g, u8* l) {
    __builtin_amdgcn_global_load_lds(
        (__attribute__((address_space(1))) void*)(void*)g,
        (__attribute__((address_space(3))) void*)l, 16, 0, 0);
}

// ------------- k_prep: scale, fp8-round, row norms (wave x 2 rows) ---------
__global__ __launch_bounds__(256) void k_prep(const float* __restrict__ samples,
                                              const float* __restrict__ x,
                                              const float* __restrict__ stdv,
                                              u8* __restrict__ dst,
                                              float* __restrict__ norm) {
    const int wid = threadIdx.x >> 6, lane = threadIdx.x & 63;
    const int row0 = blockIdx.x * 8 + wid * 2;

    float4 rstd[4];
#pragma unroll
    for (int i = 0; i < 4; ++i) {
        int c = lane + 64 * i;
        rstd[i] = make_float4(1.f, 1.f, 1.f, 1.f);
        if (c < 196) {
            float4 d = ((const float4*)stdv)[c];
            rstd[i] = make_float4(1.f / d.x, 1.f / d.y, 1.f / d.z, 1.f / d.w);
        }
    }

#pragma unroll
    for (int rr = 0; rr < 2; ++rr) {
        const int row = row0 + rr;
        const float* src = (row < N_ROWS) ? samples + (size_t)row * D_DIM
                                          : x + (size_t)(row - N_ROWS) * D_DIM;
        unsigned* drow = (unsigned*)(dst + (size_t)row * KPB);
        float sq = 0.f;
#pragma unroll
        for (int i = 0; i < 4; ++i) {
            const int c = lane + 64 * i;       // u32 chunk (4 fp8)
            if (c < 224) {                     // 224*4 = 896 = KPB
                unsigned p = 0;
                if (c < 196) {                 // 196*4 = 784 = D
                    float4 s = ((const float4*)src)[c];
                    float ux = s.x * rstd[i].x, uy = s.y * rstd[i].y;
                    float uz = s.z * rstd[i].z, uw = s.w * rstd[i].w;
                    p = __builtin_amdgcn_cvt_pk_fp8_f32(ux, uy, 0, false);
                    p = __builtin_amdgcn_cvt_pk_fp8_f32(uz, uw, p, true);
                    float r0 = __builtin_amdgcn_cvt_f32_fp8(p, 0);
                    float r1 = __builtin_amdgcn_cvt_f32_fp8(p, 1);
                    float r2 = __builtin_amdgcn_cvt_f32_fp8(p, 2);
                    float r3 = __builtin_amdgcn_cvt_f32_fp8(p, 3);
                    sq += r0 * r0 + r1 * r1 + r2 * r2 + r3 * r3;  // norm of ROUNDED
                }
                drow[c] = p;
            }
        }
        for (int m = 32; m; m >>= 1) sq += __shfl_xor(sq, m);
        if (lane == 0) norm[row] = sq;
    }
}

// ---------------- k_gemm: 256x256 tile, 16x16x128, kt64 ring of 4 ----------
// LDS slot u&3 at (u&3)*32768: A 256x64B @ +0, B 256x64B @ +16384.
// Slot chunk c of row r holds global K-granule c ^ ((r>>1)&3).
// Tile T = slots {2T,2T+1}, base (T&1)*65536.
// 16x16x128 frag: lane l: row = l&15, k-bytes [32*(l>>4), +32) -> sub-slot
// (g>>1)*32768, chunks {(2*(g&1))^key, ^1} -> b128 at addr, addr^16.
// C/D: col = lane&15, row-in-16 = (lane>>4)*4 + reg.   (all R9-verified)
__global__ __launch_bounds__(512, 2) void k_gemm(const u8* __restrict__ U,
                                                 const u8* __restrict__ V,
                                                 const float* __restrict__ vnorm,
                                                 float* __restrict__ pmax,
                                                 float* __restrict__ psum) {
    __shared__ __align__(16) char smem[131072];  // 4x32KB ring; epi overlay
    float2* part = (float2*)smem;                // [256][64] epilogue partials

    const int tid = threadIdx.x;
    const int lane = tid & 63;
    const int wid = tid >> 6;              // 0..7
    const int waveRow = wid >> 2;          // 0..1 (128-row half)
    const int waveCol = wid & 3;           // 0..3 (64-col quarter)

    // XCD-bijective swizzle: nwg=512, 512%8==0 -> wg=(bid%8)*64+bid/8.
    // XCD x gets 64 consecutive logical tiles = bRows [4x,4x+4) x all bCols.
    const int bid = blockIdx.y * 16 + blockIdx.x;
    const int wg = (bid & 7) * 64 + (bid >> 3);
    const int bRow = wg >> 4;              // 0..31
    const int bCol = wg & 15;              // 0..15
    const int g = lane >> 4, rl = lane & 15;

    // ---- staging: per kt64 slot, 2 A + 2 B gld16/thread (R9 formulas).
    const int r4 = lane >> 2;
    const int gc = (lane & 3) ^ ((lane >> 3) & 3);
    const u8* gA[2]; int lo[2];
#pragma unroll
    for (int q = 0; q < 2; ++q) {
        const int row = wid * 32 + q * 16 + r4;     // 0..255
        gA[q] = U + (size_t)(bRow * 256 + row) * KPB + gc * 16;
        lo[q] = wid * 2048 + q * 1024;              // wave-uniform LDS offset
    }
    const ptrdiff_t dBA = (V - U) +
        ((ptrdiff_t)bCol * 256 - (ptrdiff_t)bRow * 256) * (ptrdiff_t)KPB;

    // ---- frag-read offsets (relative to tile base (T&1)*65536)
    const int key = (rl >> 1) & 3;
    const int slotL = (2 * (g & 1)) ^ key;
    const int aoff = (g >> 1) * 32768 + (waveRow * 128 + rl) * 64 + slotL * 16;         // +i*1024
    const int boff = (g >> 1) * 32768 + 16384 + (waveCol * 64 + rl) * 64 + slotL * 16;  // +j*1024

    f32x4 acc[8][4];
#pragma unroll
    for (int i = 0; i < 8; ++i)
#pragma unroll
        for (int j = 0; j < 4; ++j) acc[i][j] = (f32x4){0.f, 0.f, 0.f, 0.f};

#define ISSUE(u) { \
    u8* lb = (u8*)smem + ((u) & 3) * 32768; \
    const int ko = (u) * 64; \
    gld16(gA[0] + ko, lb + lo[0]); \
    gld16(gA[0] + dBA + ko, lb + 16384 + lo[0]); \
    gld16(gA[1] + ko, lb + lo[1]); \
    gld16(gA[1] + dBA + ko, lb + 16384 + lo[1]); }

#define ISSUE_TILE(T) { ISSUE(2*(T)); ISSUE(2*(T)+1); }

#define LOADFRAG(dst, off) { \
    int4 L_ = *(const int4*)(base + (off)); \
    int4 H_ = *(const int4*)(base + ((off) ^ 16)); \
    dst = (i32x8){L_.x, L_.y, L_.z, L_.w, H_.x, H_.y, H_.z, H_.w}; }

    // prologue: stage EXACTLY the ring capacity (tiles 0,1 -> slots 0-3).
    ISSUE_TILE(0); ISSUE_TILE(1);          // 16 loads in flight
    __builtin_amdgcn_s_waitcnt(0x0F78);    // vmcnt(8): tile 0 landed
    __builtin_amdgcn_s_barrier();          // tile 0 published to all waves

#pragma unroll
    for (int T = 0; T < 7; ++T) {
        const char* base = smem + (T & 1) * 65536;
        i32x8 b0, b1, b2, b3;
        LOADFRAG(b0, boff);
        LOADFRAG(b1, boff + 1024);
        LOADFRAG(b2, boff + 2 * 1024);
        LOADFRAG(b3, boff + 3 * 1024);
        __builtin_amdgcn_s_setprio(1);
#pragma unroll
        for (int i = 0; i < 8; ++i) {
            i32x8 ai;
            LOADFRAG(ai, aoff + i * 1024);
            acc[i][0] = __builtin_amdgcn_mfma_scale_f32_16x16x128_f8f6f4(
                ai, b0, acc[i][0], 0, 0, 0, 127, 0, 127);
            acc[i][1] = __builtin_amdgcn_mfma_scale_f32_16x16x128_f8f6f4(
                ai, b1, acc[i][1], 0, 0, 0, 127, 0, 127);
            acc[i][2] = __builtin_amdgcn_mfma_scale_f32_16x16x128_f8f6f4(
                ai, b2, acc[i][2], 0, 0, 0, 127, 0, 127);
            acc[i][3] = __builtin_amdgcn_mfma_scale_f32_16x16x128_f8f6f4(
                ai, b3, acc[i][3], 0, 0, 0, 127, 0, 127);
        }
        __builtin_amdgcn_s_setprio(0);

        if (T < 6) {
            // own tile-(T+1) loads are the ONLY outstanding VMEM (T+2 not
            // yet issued) and were issued one full compute-tile ago.
            __builtin_amdgcn_s_waitcnt(0x0F70);   // vmcnt(0)
        }
        __builtin_amdgcn_s_barrier();  // publishes T+1; all reads of T done
        if (T < 5) ISSUE_TILE(T + 2);  // into T's freed slots, 1-tile flight
    }
#undef LOADFRAG
#undef ISSUE_TILE
#undef ISSUE

    // ---- epilogue: w = dot - 0.5*vn; j-combine (4 cols) -> [256][64] ----
    float vn[4];
#pragma unroll
    for (int j = 0; j < 4; ++j) vn[j] = vnorm[bCol * 256 + waveCol * 64 + j * 16 + rl];
    __syncthreads();   // drain before partials overlay the ring

    const int prow0 = waveRow * 128 + g * 4;
    const int pc = waveCol * 16 + rl;
#pragma unroll
    for (int i = 0; i < 8; ++i) {
#pragma unroll
        for (int r = 0; r < 4; ++r) {
            float w0 = acc[i][0][r] - 0.5f * vn[0];
            float w1 = acc[i][1][r] - 0.5f * vn[1];
            float w2 = acc[i][2][r] - 0.5f * vn[2];
            float w3 = acc[i][3][r] - 0.5f * vn[3];
            float m = fmaxf(fmaxf(w0, w1), fmaxf(w2, w3));
            float s = __expf(w0 - m) + __expf(w1 - m) + __expf(w2 - m) + __expf(w3 - m);
            part[(prow0 + i * 16 + r) * 64 + pc] = make_float2(m, s);
        }
    }
    __syncthreads();
    if (tid < 256) {
        const int row = tid;                       // 0..255
        const float2* p = part + row * 64;
        const int rot = row & 63;                  // rotated start: min-conflict
        float m = -3.4e38f;
#pragma unroll 8
        for (int q = 0; q < 64; ++q) m = fmaxf(m, p[(q + rot) & 63].x);
        float s = 0.f;
#pragma unroll 8
        for (int q = 0; q < 64; ++q) { float2 v = p[(q + rot) & 63]; s += v.y * __expf(v.x - m); }
        size_t grow = (size_t)(bRow * 256 + row);
        // transposed layout [bCol][row]: contiguous per-block stores
        pmax[(size_t)bCol * N_ROWS + grow] = m;
        psum[(size_t)bCol * N_ROWS + grow] = s;
    }
}

// --------------- k_final: combine 16 partials + row constants --------------
__global__ __launch_bounds__(256) void k_final(const float* __restrict__ pmax,
                                               const float* __restrict__ psum,
                                               const float* __restrict__ norm,
                                               const float* __restrict__ stdv,
                                               float* __restrict__ out) {
    __shared__ float wsum[4];
    const int t = threadIdx.x;
    float ls = 0.f;
    for (int d = t; d < D_DIM; d += 256) ls += logf(stdv[d]);
    for (int m = 32; m; m >>= 1) ls += __shfl_xor(ls, m);
    if ((t & 63) == 0) wsum[t >> 6] = ls;
    __syncthreads();
    const float logc = -0.5f * (float)D_DIM * LOG2PI - (wsum[0] + wsum[1] + wsum[2] + wsum[3]);

    const int n = blockIdx.x * 256 + t;
    // transposed partials: pmax[c*N_ROWS + n]
    float gm = pmax[n];
#pragma unroll
    for (int c = 1; c < 16; ++c) gm = fmaxf(gm, pmax[(size_t)c * N_ROWS + n]);
    float S = 0.f;
#pragma unroll
    for (int c = 0; c < 16; ++c)
        S += psum[(size_t)c * N_ROWS + n] * __expf(pmax[(size_t)c * N_ROWS + n] - gm);
    out[n] = gm + logf(S) - 0.5f * norm[n] + logc - LOGM;
}

// ---------------------------------------------------------------------------
extern "C" void kernel_launch(void* const* d_in, const int* in_sizes, int n_in,
                              void* d_out, int out_size, void* d_ws, size_t ws_size,
                              hipStream_t stream) {
    const float* samples = (const float*)d_in[0];  // 8192*784
    const float* x       = (const float*)d_in[1];  // 4096*784
    const float* stdv    = (const float*)d_in[2];  // 784
    float* out = (float*)d_out;                    // 8192

    char* ws = (char*)d_ws;
    // U fp8 (8192*896) | V fp8 (4096*896) | norm (12288 f32) | pmax | psum
    u8*    U    = (u8*)ws;                        //  7,340,032 B
    u8*    V    = (u8*)(ws + 7340032);            //  3,670,016 B
    float* norm = (float*)(ws + 11010048);        //     49,152 B
    float* pmax = (float*)(ws + 11059200);        //    524,288 B
    float* psum = (float*)(ws + 11583488);        //    524,288 B  (total ~12.1 MB)

    k_prep<<<(N_ROWS + M_ROWS) / 8, 256, 0, stream>>>(samples, x, stdv, U, norm);
    k_gemm<<<dim3(M_ROWS / 256, N_ROWS / 256), 512, 0, stream>>>(U, V, norm + N_ROWS, pmax, psum);
    k_final<<<N_ROWS / 256, 256, 0, stream>>>(pmax, psum, norm, stdv, out);
}